// Round 2
// baseline (2272.853 us; speedup 1.0000x reference)
//
#include <hip/hip_runtime.h>
#include <hip/hip_bf16.h>

typedef unsigned short u16;

#define NN 60000
#define NE 240000

__device__ __forceinline__ float bf2f(u16 u) {
    union { unsigned int i; float f; } v; v.i = ((unsigned int)u) << 16; return v.f;
}
__device__ __forceinline__ u16 f2bf(float f) {
    __hip_bfloat16 h = __float2bfloat16(f);
    return *reinterpret_cast<u16*>(&h);
}
__device__ __forceinline__ float softplusf(float x) {
    return fmaxf(x, 0.f) + log1pf(expf(-fabsf(x)));
}

// dtype-generic scalar load: B=true -> bf16 (u16), B=false -> float32
template<bool B>
__device__ __forceinline__ float LD(const void* p, int i) {
    if constexpr (B) return bf2f(((const u16*)p)[i]);
    else             return ((const float*)p)[i];
}

// ---------------------------------------------------------------------------
// dtype detection: sample even-indexed u16s of x. bf16 N(0,1) values have
// exponent field ~127 (>95% in [112,143]); f32 low-mantissa halves are
// uniform (~12.5% in range). Majority vote -> flag.
// ---------------------------------------------------------------------------
__global__ void detect_kernel(const u16* __restrict__ x, int* __restrict__ flag) {
    __shared__ int cnt;
    if (threadIdx.x == 0) cnt = 0;
    __syncthreads();
    int c = 0;
    for (int i = threadIdx.x; i < 2048; i += 256) {
        u16 w = x[2 * i];
        int e = (w >> 7) & 0xFF;
        if (e >= 112 && e <= 143) c++;
    }
    atomicAdd(&cnt, c);
    __syncthreads();
    if (threadIdx.x == 0) *flag = (cnt > 1024) ? 1 : 0;
}

// ---------------------------------------------------------------------------
// Edge stage: 8 edges per 256-thread block.
// ---------------------------------------------------------------------------
struct EdgeSmem {
    __align__(16) float msgT[256][8];   // [k][edge]
    __align__(16) float uT[32][8];      // [d][edge]
    float wL[64], sL[64];
    float embL[8][32];
    float moaL[8][2];
    float diffL[8][2];
    int   ei0s[8], ei1s[8];
};

template<bool B>
__device__ void edge_body(EdgeSmem& sm,
    const void* x, const int* edge_idx, const int* edge_attr,
    const void* node_elec, const void* lora_down, const void* lora_up,
    const void* emb_edge, const void* moa_w, const void* moa_s,
    const void* elec_lin, const void* lin_pre, float* agg, int g, int j)
{
    // moa tables (per row c of 32, normalized)
    if (j < 64) {
        int c = j >> 5;
        float sw = softplusf(LD<B>(moa_w, j));
        float tot = 0.f;
        #pragma unroll
        for (int d = 0; d < 32; d++) tot += softplusf(LD<B>(moa_w, c * 32 + d));
        sm.wL[j] = sw / tot;
        sm.sL[j] = softplusf(LD<B>(moa_s, j));
    }
    if (j < 16) {
        int s = j >> 1, c = j & 1;
        int e = g * 8 + s;
        int a = edge_idx[e], b = edge_idx[NE + e];
        if (c == 0) { sm.ei0s[s] = a; sm.ei1s[s] = b; }
        sm.diffL[s][c] = LD<B>(node_elec, a * 2 + c) - LD<B>(node_elec, b * 2 + c);
    }
    __syncthreads();
    if (j < 16) {
        int s = j >> 1, c = j & 1;
        float df = sm.diffL[s][c], acc = 0.f;
        #pragma unroll
        for (int d = 0; d < 32; d++)
            acc += tanhf(df * sm.sL[c * 32 + d]) * sm.wL[c * 32 + d];
        sm.moaL[s][c] = acc;
    }
    #pragma unroll
    for (int s = 0; s < 8; s++)
        sm.msgT[j][s] = LD<B>(x, sm.ei0s[s] * 256 + j) + LD<B>(x, sm.ei1s[s] * 256 + j);
    __syncthreads();
    {   // edge embedding [8 edges x 32 dims]
        int s = j >> 5, d = j & 31, e = g * 8 + s;
        sm.embL[s][d] = LD<B>(emb_edge, edge_attr[e * 3 + 0] * 32 + d)
                      + LD<B>(emb_edge, edge_attr[e * 3 + 1] * 32 + d)
                      + LD<B>(emb_edge, edge_attr[e * 3 + 2] * 32 + d)
                      + sm.moaL[s][0] * LD<B>(elec_lin, d)
                      + sm.moaL[s][1] * LD<B>(elec_lin, 32 + d);
    }
    __syncthreads();
    {   // LoRA down (K=256) then modulate by emb
        int s = j >> 5, d = j & 31;
        float t = 0.f;
        for (int k = 0; k < 256; k++)
            t = fmaf(sm.msgT[k][s], LD<B>(lora_down, k * 32 + d), t);
        sm.uT[d][s] = t * sm.embL[s][d];
    }
    __syncthreads();
    // main matvec: lin_pre (K=256) + lora_up (K=32)
    float acc[8];
    #pragma unroll
    for (int s = 0; s < 8; s++) acc[s] = 0.f;
    #pragma unroll 4
    for (int k = 0; k < 256; k++) {
        float w = LD<B>(lin_pre, k * 256 + j);
        const float4 m0 = *reinterpret_cast<const float4*>(&sm.msgT[k][0]);
        const float4 m1 = *reinterpret_cast<const float4*>(&sm.msgT[k][4]);
        acc[0] = fmaf(m0.x, w, acc[0]); acc[1] = fmaf(m0.y, w, acc[1]);
        acc[2] = fmaf(m0.z, w, acc[2]); acc[3] = fmaf(m0.w, w, acc[3]);
        acc[4] = fmaf(m1.x, w, acc[4]); acc[5] = fmaf(m1.y, w, acc[5]);
        acc[6] = fmaf(m1.z, w, acc[6]); acc[7] = fmaf(m1.w, w, acc[7]);
    }
    #pragma unroll 4
    for (int d = 0; d < 32; d++) {
        float w = LD<B>(lora_up, d * 256 + j);
        const float4 u0 = *reinterpret_cast<const float4*>(&sm.uT[d][0]);
        const float4 u1 = *reinterpret_cast<const float4*>(&sm.uT[d][4]);
        acc[0] = fmaf(u0.x, w, acc[0]); acc[1] = fmaf(u0.y, w, acc[1]);
        acc[2] = fmaf(u0.z, w, acc[2]); acc[3] = fmaf(u0.w, w, acc[3]);
        acc[4] = fmaf(u1.x, w, acc[4]); acc[5] = fmaf(u1.y, w, acc[5]);
        acc[6] = fmaf(u1.z, w, acc[6]); acc[7] = fmaf(u1.w, w, acc[7]);
    }
    #pragma unroll
    for (int s = 0; s < 8; s++)
        unsafeAtomicAdd(&agg[sm.ei1s[s] * 256 + j], acc[s]);
}

__global__ __launch_bounds__(256) void edge_kernel(
    const void* x, const int* edge_idx, const int* edge_attr,
    const void* node_elec, const void* lora_down, const void* lora_up,
    const void* emb_edge, const void* moa_w, const void* moa_s,
    const void* elec_lin, const void* lin_pre, float* agg, const int* flag)
{
    __shared__ EdgeSmem sm;
    const int j = threadIdx.x, g = blockIdx.x;
    if (*flag) edge_body<true >(sm, x, edge_idx, edge_attr, node_elec, lora_down,
                                lora_up, emb_edge, moa_w, moa_s, elec_lin, lin_pre, agg, g, j);
    else       edge_body<false>(sm, x, edge_idx, edge_attr, node_elec, lora_down,
                                lora_up, emb_edge, moa_w, moa_s, elec_lin, lin_pre, agg, g, j);
}

// ---------------------------------------------------------------------------
// Node stage: 8 nodes per 256-thread block, fully fused.
// ---------------------------------------------------------------------------
struct NodeSmem {
    __align__(16) float aggT[256][8];
    float gL[8][256];
    float vL[8][256];
    float ghat[256], vhat[256];
    float xxL[1024];
};

template<bool B>
__device__ void node_body(NodeSmem& sm,
    const float* agg, const int* deg, const void* emb_deg,
    const void* gate_lin, const void* value_lin, const void* gate_kernel,
    const void* value_kernel, const void* act_bias, const void* post_kernel,
    void* out, int n0, int j)
{
    #pragma unroll
    for (int s = 0; s < 8; s++) sm.aggT[j][s] = agg[(n0 + s) * 256 + j];
    __syncthreads();

    float ga[8], va[8];
    #pragma unroll
    for (int s = 0; s < 8; s++) { ga[s] = 0.f; va[s] = 0.f; }
    #pragma unroll 4
    for (int k = 0; k < 256; k++) {
        float wg = LD<B>(gate_lin,  k * 256 + j);
        float wv = LD<B>(value_lin, k * 256 + j);
        const float4 a0 = *reinterpret_cast<const float4*>(&sm.aggT[k][0]);
        const float4 a1 = *reinterpret_cast<const float4*>(&sm.aggT[k][4]);
        ga[0] = fmaf(a0.x, wg, ga[0]); va[0] = fmaf(a0.x, wv, va[0]);
        ga[1] = fmaf(a0.y, wg, ga[1]); va[1] = fmaf(a0.y, wv, va[1]);
        ga[2] = fmaf(a0.z, wg, ga[2]); va[2] = fmaf(a0.z, wv, va[2]);
        ga[3] = fmaf(a0.w, wg, ga[3]); va[3] = fmaf(a0.w, wv, va[3]);
        ga[4] = fmaf(a1.x, wg, ga[4]); va[4] = fmaf(a1.x, wv, va[4]);
        ga[5] = fmaf(a1.y, wg, ga[5]); va[5] = fmaf(a1.y, wv, va[5]);
        ga[6] = fmaf(a1.z, wg, ga[6]); va[6] = fmaf(a1.z, wv, va[6]);
        ga[7] = fmaf(a1.w, wg, ga[7]); va[7] = fmaf(a1.w, wv, va[7]);
    }
    __syncthreads();
    #pragma unroll
    for (int s = 0; s < 8; s++) { sm.gL[s][j] = ga[s]; sm.vL[s][j] = va[s]; }

    const int h = j >> 5, dd = j & 31, f0 = dd << 2;
    const float lo = 0.22360679774997896f;   // 1/sqrt(20)
    const float hi = 4.47213595499957939f;   // sqrt(20)

    for (int s = 0; s < 8; s++) {
        __syncthreads();
        // per-head RMS (LDS broadcast loop over the 32 dims of head h)
        float gs = 0.f, vs = 0.f;
        #pragma unroll
        for (int d = 0; d < 32; d++) {
            float g = sm.gL[s][h * 32 + d];
            float v = sm.vL[s][h * 32 + d];
            gs = fmaf(g, g, gs); vs = fmaf(v, v, vs);
        }
        float grms = sqrtf(gs * (1.f / 32.f) + 1e-6f);
        float vrms = sqrtf(vs * (1.f / 32.f) + 1e-6f);
        float gv = sm.gL[s][j], vv = sm.vL[s][j];
        float bias = LD<B>(emb_deg, deg[n0 + s] * 256 + j);
        sm.ghat[j] = (gv / grms + bias) * 0.70710678118654752f;
        sm.vhat[j] = vv / vrms;
        __syncthreads();

        // head matmuls (K=32): thread covers head h, cols f0..f0+3
        float a0 = 0.f, a1 = 0.f, a2 = 0.f, a3 = 0.f;
        float b0 = 0.f, b1 = 0.f, b2 = 0.f, b3 = 0.f;
        #pragma unroll 4
        for (int d = 0; d < 32; d++) {
            float gh = sm.ghat[h * 32 + d];
            float vh = sm.vhat[h * 32 + d];
            int base = h * 4096 + d * 128 + f0;
            a0 = fmaf(gh, LD<B>(gate_kernel,  base + 0), a0);
            a1 = fmaf(gh, LD<B>(gate_kernel,  base + 1), a1);
            a2 = fmaf(gh, LD<B>(gate_kernel,  base + 2), a2);
            a3 = fmaf(gh, LD<B>(gate_kernel,  base + 3), a3);
            b0 = fmaf(vh, LD<B>(value_kernel, base + 0), b0);
            b1 = fmaf(vh, LD<B>(value_kernel, base + 1), b1);
            b2 = fmaf(vh, LD<B>(value_kernel, base + 2), b2);
            b3 = fmaf(vh, LD<B>(value_kernel, base + 3), b3);
        }
        int fb = h * 128 + f0;
        a0 = fminf(fmaxf(softplusf(a0 + LD<B>(act_bias, fb + 0)), lo), hi);
        a1 = fminf(fmaxf(softplusf(a1 + LD<B>(act_bias, fb + 1)), lo), hi);
        a2 = fminf(fmaxf(softplusf(a2 + LD<B>(act_bias, fb + 2)), lo), hi);
        a3 = fminf(fmaxf(softplusf(a3 + LD<B>(act_bias, fb + 3)), lo), hi);
        sm.xxL[fb + 0] = a0 * b0; sm.xxL[fb + 1] = a1 * b1;
        sm.xxL[fb + 2] = a2 * b2; sm.xxL[fb + 3] = a3 * b3;
        __syncthreads();

        // post matmul (K=128): out col = h*32 + dd
        float o = 0.f;
        #pragma unroll 4
        for (int f = 0; f < 128; f++)
            o = fmaf(sm.xxL[h * 128 + f], LD<B>(post_kernel, h * 4096 + f * 32 + dd), o);
        if constexpr (B) ((u16*)out)[(n0 + s) * 256 + j] = f2bf(o);
        else             ((float*)out)[(n0 + s) * 256 + j] = o;
    }
}

__global__ __launch_bounds__(256) void node_kernel(
    const float* agg, const int* deg, const void* emb_deg,
    const void* gate_lin, const void* value_lin, const void* gate_kernel,
    const void* value_kernel, const void* act_bias, const void* post_kernel,
    void* out, const int* flag)
{
    __shared__ NodeSmem sm;
    const int j = threadIdx.x, n0 = blockIdx.x * 8;
    if (*flag) node_body<true >(sm, agg, deg, emb_deg, gate_lin, value_lin,
                                gate_kernel, value_kernel, act_bias, post_kernel, out, n0, j);
    else       node_body<false>(sm, agg, deg, emb_deg, gate_lin, value_lin,
                                gate_kernel, value_kernel, act_bias, post_kernel, out, n0, j);
}

extern "C" void kernel_launch(void* const* d_in, const int* in_sizes, int n_in,
                              void* d_out, int out_size, void* d_ws, size_t ws_size,
                              hipStream_t stream) {
    const void* x           = d_in[0];
    const int*  deg         = (const int*)d_in[1];
    const int*  edge_idx    = (const int*)d_in[2];
    const int*  edge_attr   = (const int*)d_in[3];
    const void* node_elec   = d_in[4];
    const void* lora_down   = d_in[5];
    const void* lora_up     = d_in[6];
    const void* emb_edge    = d_in[7];
    const void* moa_w       = d_in[8];
    const void* moa_s       = d_in[9];
    const void* elec_lin    = d_in[10];
    const void* emb_deg     = d_in[11];
    const void* lin_pre     = d_in[12];
    const void* gate_lin    = d_in[13];
    const void* gate_kernel = d_in[14];
    const void* value_lin   = d_in[15];
    const void* value_kernel= d_in[16];
    const void* act_bias    = d_in[17];
    const void* post_kernel = d_in[18];

    float* agg = (float*)d_ws;                              // 61.44 MB
    int*   flag = (int*)((char*)d_ws + (size_t)NN * 256 * sizeof(float));

    hipMemsetAsync(agg, 0, (size_t)NN * 256 * sizeof(float), stream);
    detect_kernel<<<1, 256, 0, stream>>>((const u16*)x, flag);

    edge_kernel<<<NE / 8, 256, 0, stream>>>(
        x, edge_idx, edge_attr, node_elec, lora_down, lora_up, emb_edge,
        moa_w, moa_s, elec_lin, lin_pre, agg, flag);

    node_kernel<<<NN / 8, 256, 0, stream>>>(
        agg, deg, emb_deg, gate_lin, value_lin, gate_kernel, value_kernel,
        act_bias, post_kernel, d_out, flag);
}

// Round 3
// 819.118 us; speedup vs baseline: 2.7748x; 2.7748x over previous
//
#include <hip/hip_runtime.h>
#include <hip/hip_bf16.h>

typedef unsigned short u16;

#define NN 60000
#define NE 240000

typedef __attribute__((ext_vector_type(8))) short bfrag;   // 8 bf16
typedef __attribute__((ext_vector_type(4))) float ffrag;   // 4 f32

__device__ __forceinline__ float bf2f(u16 u) {
    union { unsigned int i; float f; } v; v.i = ((unsigned int)u) << 16; return v.f;
}
__device__ __forceinline__ u16 f2bf(float f) {
    __hip_bfloat16 h = __float2bfloat16(f);
    return *reinterpret_cast<u16*>(&h);
}
__device__ __forceinline__ float softplusf(float x) {
    return fmaxf(x, 0.f) + log1pf(expf(-fabsf(x)));
}
template<bool B>
__device__ __forceinline__ float LD(const void* p, int i) {
    if constexpr (B) return bf2f(((const u16*)p)[i]);
    else             return ((const float*)p)[i];
}
__device__ __forceinline__ bfrag ldfrag(const u16* p) {
    return *reinterpret_cast<const bfrag*>(p);
}
__device__ __forceinline__ ffrag MFMA(bfrag a, bfrag b, ffrag c) {
    return __builtin_amdgcn_mfma_f32_16x16x32_bf16(a, b, c, 0, 0, 0);
}

// ---------------------------------------------------------------------------
// dtype detection (bf16 vs f32 inputs), majority vote on exponent fields.
// ---------------------------------------------------------------------------
__global__ void detect_kernel(const u16* __restrict__ x, int* __restrict__ flag) {
    __shared__ int cnt;
    if (threadIdx.x == 0) cnt = 0;
    __syncthreads();
    int c = 0;
    for (int i = threadIdx.x; i < 2048; i += 256) {
        u16 w = x[2 * i];
        int e = (w >> 7) & 0xFF;
        if (e >= 112 && e <= 143) c++;
    }
    atomicAdd(&cnt, c);
    __syncthreads();
    if (threadIdx.x == 0) *flag = (cnt > 1024) ? 1 : 0;
}

// ---------------------------------------------------------------------------
// Prep: build transposed bf16 weight copies (BT layouts, k-contiguous).
// ---------------------------------------------------------------------------
template<bool B>
__device__ void prep_body(const void* gate_lin, const void* value_lin,
    const void* lin_pre, const void* lora_down, const void* lora_up,
    const void* gate_kernel, const void* value_kernel, const void* post_kernel,
    u16* gT, u16* vT, u16* lpT, u16* ldT, u16* luT, u16* gkT, u16* vkT, u16* pkT,
    int tid, int stride)
{
    for (int i = tid; i < 65536; i += stride) {
        int n = i >> 8, k = i & 255;
        gT[i]  = f2bf(LD<B>(gate_lin,  k * 256 + n));
        vT[i]  = f2bf(LD<B>(value_lin, k * 256 + n));
        lpT[i] = f2bf(LD<B>(lin_pre,   k * 256 + n));
    }
    for (int i = tid; i < 8192; i += stride) {
        { int n = i >> 8, k = i & 255; ldT[i] = f2bf(LD<B>(lora_down, k * 32 + n)); }
        { int n = i >> 5, k = i & 31;  luT[i] = f2bf(LD<B>(lora_up,   k * 256 + n)); }
    }
    for (int i = tid; i < 32768; i += stride) {
        { int hf = i >> 5, d = i & 31, h = hf >> 7, f = hf & 127;
          gkT[i] = f2bf(LD<B>(gate_kernel,  h * 4096 + d * 128 + f));
          vkT[i] = f2bf(LD<B>(value_kernel, h * 4096 + d * 128 + f)); }
        { int hd = i >> 7, f = i & 127, h = hd >> 5, d2 = hd & 31;
          pkT[i] = f2bf(LD<B>(post_kernel, h * 4096 + f * 32 + d2)); }
    }
}
__global__ void prep_kernel(const void* gate_lin, const void* value_lin,
    const void* lin_pre, const void* lora_down, const void* lora_up,
    const void* gate_kernel, const void* value_kernel, const void* post_kernel,
    u16* gT, u16* vT, u16* lpT, u16* ldT, u16* luT, u16* gkT, u16* vkT, u16* pkT,
    const int* flag)
{
    int tid = blockIdx.x * blockDim.x + threadIdx.x;
    int stride = gridDim.x * blockDim.x;
    if (*flag) prep_body<true >(gate_lin, value_lin, lin_pre, lora_down, lora_up,
        gate_kernel, value_kernel, post_kernel, gT, vT, lpT, ldT, luT, gkT, vkT, pkT, tid, stride);
    else       prep_body<false>(gate_lin, value_lin, lin_pre, lora_down, lora_up,
        gate_kernel, value_kernel, post_kernel, gT, vT, lpT, ldT, luT, gkT, vkT, pkT, tid, stride);
}

// ---------------------------------------------------------------------------
// MFMA edge kernel: 64 edges / block (4 waves x 16-row tiles).
// ---------------------------------------------------------------------------
struct EdgeSmemM {
    __align__(16) u16 msgB[64][264];   // 33792 B, stride 528B -> 4-bank row step
    __align__(16) u16 uB[64][40];      // 5120 B, stride 80B
    __align__(16) float embL[64][32];  // 8192 B
    float wL[64], sL[64];
    float moaL[64][2];
    int ei0s[64], ei1s[64];
};

template<bool B>
__device__ void edge_body_m(EdgeSmemM& sm, const void* x, const int* edge_idx,
    const int* edge_attr, const void* node_elec, const void* emb_edge,
    const void* moa_w, const void* moa_s, const void* elec_lin,
    const u16* ldT, const u16* luT, const u16* lpT, float* agg, int g, int j)
{
    const int w = j >> 6, quad = (j >> 4) & 3, l15 = j & 15;
    const int lane = j & 63;

    if (w == 0) {
        int c = lane >> 5;
        float sw = softplusf(LD<B>(moa_w, lane));
        float tot = 0.f;
        #pragma unroll
        for (int d = 0; d < 32; d++) tot += softplusf(LD<B>(moa_w, c * 32 + d));
        sm.wL[lane] = sw / tot;
        sm.sL[lane] = softplusf(LD<B>(moa_s, lane));
        int e = g * 64 + lane;
        int a = edge_idx[e], b = edge_idx[NE + e];
        sm.ei0s[lane] = a; sm.ei1s[lane] = b;
        #pragma unroll
        for (int c2 = 0; c2 < 2; c2++) {
            float df = LD<B>(node_elec, a * 2 + c2) - LD<B>(node_elec, b * 2 + c2);
            float acc = 0.f;
            for (int d = 0; d < 32; d++)
                acc += tanhf(df * sm.sL[c2 * 32 + d]) * sm.wL[c2 * 32 + d];
            sm.moaL[lane][c2] = acc;
        }
    }
    __syncthreads();

    // gather msg -> bf16 LDS (4 threads per edge row)
    {
        int row = j >> 2, seg = j & 3, c0 = seg * 64;
        int e0 = sm.ei0s[row], e1 = sm.ei1s[row];
        if constexpr (B) {
            const u16* xp = (const u16*)x;
            for (int cc = 0; cc < 64; cc += 8) {
                bfrag v0 = ldfrag(xp + (size_t)e0 * 256 + c0 + cc);
                bfrag v1 = ldfrag(xp + (size_t)e1 * 256 + c0 + cc);
                bfrag o;
                #pragma unroll
                for (int q = 0; q < 8; q++)
                    o[q] = (short)f2bf(bf2f((u16)v0[q]) + bf2f((u16)v1[q]));
                *reinterpret_cast<bfrag*>(&sm.msgB[row][c0 + cc]) = o;
            }
        } else {
            const float* xp = (const float*)x;
            for (int cc = 0; cc < 64; cc += 4) {
                float4 v0 = *(const float4*)(xp + (size_t)e0 * 256 + c0 + cc);
                float4 v1 = *(const float4*)(xp + (size_t)e1 * 256 + c0 + cc);
                ushort4 o = { f2bf(v0.x + v1.x), f2bf(v0.y + v1.y),
                              f2bf(v0.z + v1.z), f2bf(v0.w + v1.w) };
                *reinterpret_cast<ushort4*>(&sm.msgB[row][c0 + cc]) = o;
            }
        }
        // edge embedding (4 threads x 8 dims per edge)
        int e = row, d0 = seg * 8, ea = g * 64 + e;
        int a0 = edge_attr[ea * 3 + 0], a1 = edge_attr[ea * 3 + 1], a2 = edge_attr[ea * 3 + 2];
        float m0 = sm.moaL[e][0], m1 = sm.moaL[e][1];
        #pragma unroll
        for (int d = d0; d < d0 + 8; d++) {
            sm.embL[e][d] = LD<B>(emb_edge, a0 * 32 + d) + LD<B>(emb_edge, a1 * 32 + d)
                          + LD<B>(emb_edge, a2 * 32 + d)
                          + m0 * LD<B>(elec_lin, d) + m1 * LD<B>(elec_lin, 32 + d);
        }
    }
    __syncthreads();

    const int r0 = w * 16;
    // A fragments for K=256, reused by lora-down and main GEMM
    bfrag A[8];
    #pragma unroll
    for (int kt = 0; kt < 8; kt++)
        A[kt] = ldfrag(&sm.msgB[r0 + l15][kt * 32 + quad * 8]);

    // lora-down (N=32 -> 2 tiles), modulate by emb, store uB bf16
    #pragma unroll
    for (int t = 0; t < 2; t++) {
        int n0 = t * 16;
        ffrag acc = {0.f, 0.f, 0.f, 0.f};
        #pragma unroll
        for (int kt = 0; kt < 8; kt++)
            acc = MFMA(A[kt], ldfrag(ldT + (n0 + l15) * 256 + kt * 32 + quad * 8), acc);
        #pragma unroll
        for (int r = 0; r < 4; r++) {
            int row = r0 + quad * 4 + r;
            sm.uB[row][n0 + l15] = f2bf(acc[r] * sm.embL[row][n0 + l15]);
        }
    }
    bfrag uA = ldfrag(&sm.uB[r0 + l15][quad * 8]);

    int er[4];
    #pragma unroll
    for (int r = 0; r < 4; r++) er[r] = sm.ei1s[r0 + quad * 4 + r];

    // main: msg@lin_pre (K=256) + u@lora_up (K=32), scatter atomics
    for (int t = 0; t < 16; t++) {
        int n0 = t * 16;
        ffrag acc = {0.f, 0.f, 0.f, 0.f};
        #pragma unroll
        for (int kt = 0; kt < 8; kt++)
            acc = MFMA(A[kt], ldfrag(lpT + (n0 + l15) * 256 + kt * 32 + quad * 8), acc);
        acc = MFMA(uA, ldfrag(luT + (n0 + l15) * 32 + quad * 8), acc);
        #pragma unroll
        for (int r = 0; r < 4; r++)
            unsafeAtomicAdd(&agg[(size_t)er[r] * 256 + n0 + l15], acc[r]);
    }
}

__global__ __launch_bounds__(256) void edge_kernel_m(
    const void* x, const int* edge_idx, const int* edge_attr,
    const void* node_elec, const void* emb_edge, const void* moa_w,
    const void* moa_s, const void* elec_lin,
    const u16* ldT, const u16* luT, const u16* lpT, float* agg, const int* flag)
{
    __shared__ EdgeSmemM sm;
    const int j = threadIdx.x, g = blockIdx.x;
    if (*flag) edge_body_m<true >(sm, x, edge_idx, edge_attr, node_elec, emb_edge,
                                  moa_w, moa_s, elec_lin, ldT, luT, lpT, agg, g, j);
    else       edge_body_m<false>(sm, x, edge_idx, edge_attr, node_elec, emb_edge,
                                  moa_w, moa_s, elec_lin, ldT, luT, lpT, agg, g, j);
}

// ---------------------------------------------------------------------------
// MFMA node kernel: 16 nodes / block, fully fused.
// ---------------------------------------------------------------------------
struct NodeSmemM {
    union U1 {
        u16 aggB[16][264];
        u16 ghatB[16][264];
    } u1;                                  // 8448 B
    union U2 {
        struct P { float gF[16][260]; float vF[16][260]; } p;   // 33280 B
        u16 xxB[16][1032];                                      // 33024 B
    } u2;
    __align__(16) u16 vhatB[16][264];      // 8448 B
    float grmsL[16][8], vrmsL[16][8];
    int degL[16];
};

template<bool B>
__device__ void node_body_m(NodeSmemM& sm, const float* agg, const int* deg,
    const void* emb_deg, const void* act_bias, const u16* gT, const u16* vT,
    const u16* gkT, const u16* vkT, const u16* pkT, void* out, int blk, int j)
{
    const int w = j >> 6, quad = (j >> 4) & 3, l15 = j & 15;
    const int n0g = blk * 16;

    // 1. agg -> bf16 LDS
    {
        int row = j >> 4, c0 = l15 * 16;
        const float* ap = agg + (size_t)(n0g + row) * 256 + c0;
        #pragma unroll
        for (int q = 0; q < 16; q += 4) {
            float4 v = *(const float4*)(ap + q);
            ushort4 o = { f2bf(v.x), f2bf(v.y), f2bf(v.z), f2bf(v.w) };
            *reinterpret_cast<ushort4*>(&sm.u1.aggB[row][c0 + q]) = o;
        }
        if (j < 16) sm.degL[j] = deg[n0g + j];
    }
    __syncthreads();

    // 2. GEMM1: g1 = agg@gate_lin, v1 = agg@value_lin
    {
        bfrag A[8];
        #pragma unroll
        for (int kt = 0; kt < 8; kt++)
            A[kt] = ldfrag(&sm.u1.aggB[l15][kt * 32 + quad * 8]);
        const u16* WT = (w >> 1) ? vT : gT;
        float (*OF)[260] = (w >> 1) ? sm.u2.p.vF : sm.u2.p.gF;
        int half = (w & 1) * 128;
        #pragma unroll
        for (int t = 0; t < 8; t++) {
            int n0 = half + t * 16;
            ffrag acc = {0.f, 0.f, 0.f, 0.f};
            #pragma unroll
            for (int kt = 0; kt < 8; kt++)
                acc = MFMA(A[kt], ldfrag(WT + (n0 + l15) * 256 + kt * 32 + quad * 8), acc);
            #pragma unroll
            for (int r = 0; r < 4; r++)
                OF[quad * 4 + r][n0 + l15] = acc[r];
        }
    }
    __syncthreads();

    // 3. per-(row,head) RMS
    if (j < 128) {
        int r = j >> 3, h = j & 7;
        float gs = 0.f, vs = 0.f;
        #pragma unroll
        for (int d = 0; d < 32; d++) {
            float g = sm.u2.p.gF[r][h * 32 + d]; gs = fmaf(g, g, gs);
            float v = sm.u2.p.vF[r][h * 32 + d]; vs = fmaf(v, v, vs);
        }
        sm.grmsL[r][h] = 1.f / sqrtf(gs * (1.f / 32.f) + 1e-6f);
        sm.vrmsL[r][h] = 1.f / sqrtf(vs * (1.f / 32.f) + 1e-6f);
    }
    __syncthreads();

    // 4. ghat/vhat -> bf16 (ghatB overlays dead aggB)
    {
        int row = j >> 4, c0 = l15 * 16;
        int dg = sm.degL[row];
        #pragma unroll
        for (int c = c0; c < c0 + 16; c++) {
            float gi = sm.grmsL[row][c >> 5], vi = sm.vrmsL[row][c >> 5];
            float bias = LD<B>(emb_deg, dg * 256 + c);
            sm.vhatB[row][c] = f2bf(sm.u2.p.vF[row][c] * vi);
            sm.u1.ghatB[row][c] = f2bf((sm.u2.p.gF[row][c] * gi + bias) * 0.70710678118654752f);
        }
    }
    __syncthreads();

    // 5. head matmuls (K=32) + fused softplus/clip/mul epilogue -> xxB
    #pragma unroll
    for (int hh = 0; hh < 2; hh++) {
        int h = w * 2 + hh;
        bfrag aG = ldfrag(&sm.u1.ghatB[l15][h * 32 + quad * 8]);
        bfrag aV = ldfrag(&sm.vhatB[l15][h * 32 + quad * 8]);
        #pragma unroll
        for (int t = 0; t < 8; t++) {
            int n0 = t * 16;
            ffrag zero = {0.f, 0.f, 0.f, 0.f};
            ffrag ag = MFMA(aG, ldfrag(gkT + (h * 128 + n0 + l15) * 32 + quad * 8), zero);
            ffrag av = MFMA(aV, ldfrag(vkT + (h * 128 + n0 + l15) * 32 + quad * 8), zero);
            int cc = h * 128 + n0 + l15;
            float bias = LD<B>(act_bias, cc);
            #pragma unroll
            for (int r = 0; r < 4; r++) {
                float a = softplusf(ag[r] + bias);
                a = fminf(fmaxf(a, 0.22360679774997896f), 4.47213595499957939f);
                sm.u2.xxB[quad * 4 + r][cc] = f2bf(a * av[r]);
            }
        }
    }
    __syncthreads();

    // 6. post matmul (K=128) -> out
    #pragma unroll
    for (int hh = 0; hh < 2; hh++) {
        int h = w * 2 + hh;
        bfrag A4[4];
        #pragma unroll
        for (int kt = 0; kt < 4; kt++)
            A4[kt] = ldfrag(&sm.u2.xxB[l15][h * 128 + kt * 32 + quad * 8]);
        #pragma unroll
        for (int t = 0; t < 2; t++) {
            int n0 = t * 16;
            ffrag acc = {0.f, 0.f, 0.f, 0.f};
            #pragma unroll
            for (int kt = 0; kt < 4; kt++)
                acc = MFMA(A4[kt], ldfrag(pkT + (h * 32 + n0 + l15) * 128 + kt * 32 + quad * 8), acc);
            #pragma unroll
            for (int r = 0; r < 4; r++) {
                size_t idx = (size_t)(n0g + quad * 4 + r) * 256 + h * 32 + n0 + l15;
                if constexpr (B) ((u16*)out)[idx] = f2bf(acc[r]);
                else             ((float*)out)[idx] = acc[r];
            }
        }
    }
}

__global__ __launch_bounds__(256) void node_kernel_m(
    const float* agg, const int* deg, const void* emb_deg, const void* act_bias,
    const u16* gT, const u16* vT, const u16* gkT, const u16* vkT, const u16* pkT,
    void* out, const int* flag)
{
    __shared__ NodeSmemM sm;
    const int j = threadIdx.x, blk = blockIdx.x;
    if (*flag) node_body_m<true >(sm, agg, deg, emb_deg, act_bias, gT, vT, gkT, vkT, pkT, out, blk, j);
    else       node_body_m<false>(sm, agg, deg, emb_deg, act_bias, gT, vT, gkT, vkT, pkT, out, blk, j);
}

// ===========================================================================
// Fallback (round-2 proven VALU kernels) — used only if ws_size is too small.
// ===========================================================================
struct EdgeSmemFB {
    __align__(16) float msgT[256][8];
    __align__(16) float uT[32][8];
    float wL[64], sL[64];
    float embL[8][32];
    float moaL[8][2];
    float diffL[8][2];
    int   ei0s[8], ei1s[8];
};

template<bool B>
__device__ void edge_body_fb(EdgeSmemFB& sm,
    const void* x, const int* edge_idx, const int* edge_attr,
    const void* node_elec, const void* lora_down, const void* lora_up,
    const void* emb_edge, const void* moa_w, const void* moa_s,
    const void* elec_lin, const void* lin_pre, float* agg, int g, int j)
{
    if (j < 64) {
        int c = j >> 5;
        float sw = softplusf(LD<B>(moa_w, j));
        float tot = 0.f;
        #pragma unroll
        for (int d = 0; d < 32; d++) tot += softplusf(LD<B>(moa_w, c * 32 + d));
        sm.wL[j] = sw / tot;
        sm.sL[j] = softplusf(LD<B>(moa_s, j));
    }
    if (j < 16) {
        int s = j >> 1, c = j & 1;
        int e = g * 8 + s;
        int a = edge_idx[e], b = edge_idx[NE + e];
        if (c == 0) { sm.ei0s[s] = a; sm.ei1s[s] = b; }
        sm.diffL[s][c] = LD<B>(node_elec, a * 2 + c) - LD<B>(node_elec, b * 2 + c);
    }
    __syncthreads();
    if (j < 16) {
        int s = j >> 1, c = j & 1;
        float df = sm.diffL[s][c], acc = 0.f;
        #pragma unroll
        for (int d = 0; d < 32; d++)
            acc += tanhf(df * sm.sL[c * 32 + d]) * sm.wL[c * 32 + d];
        sm.moaL[s][c] = acc;
    }
    #pragma unroll
    for (int s = 0; s < 8; s++)
        sm.msgT[j][s] = LD<B>(x, sm.ei0s[s] * 256 + j) + LD<B>(x, sm.ei1s[s] * 256 + j);
    __syncthreads();
    {
        int s = j >> 5, d = j & 31, e = g * 8 + s;
        sm.embL[s][d] = LD<B>(emb_edge, edge_attr[e * 3 + 0] * 32 + d)
                      + LD<B>(emb_edge, edge_attr[e * 3 + 1] * 32 + d)
                      + LD<B>(emb_edge, edge_attr[e * 3 + 2] * 32 + d)
                      + sm.moaL[s][0] * LD<B>(elec_lin, d)
                      + sm.moaL[s][1] * LD<B>(elec_lin, 32 + d);
    }
    __syncthreads();
    {
        int s = j >> 5, d = j & 31;
        float t = 0.f;
        for (int k = 0; k < 256; k++)
            t = fmaf(sm.msgT[k][s], LD<B>(lora_down, k * 32 + d), t);
        sm.uT[d][s] = t * sm.embL[s][d];
    }
    __syncthreads();
    float acc[8];
    #pragma unroll
    for (int s = 0; s < 8; s++) acc[s] = 0.f;
    #pragma unroll 4
    for (int k = 0; k < 256; k++) {
        float w = LD<B>(lin_pre, k * 256 + j);
        const float4 m0 = *reinterpret_cast<const float4*>(&sm.msgT[k][0]);
        const float4 m1 = *reinterpret_cast<const float4*>(&sm.msgT[k][4]);
        acc[0] = fmaf(m0.x, w, acc[0]); acc[1] = fmaf(m0.y, w, acc[1]);
        acc[2] = fmaf(m0.z, w, acc[2]); acc[3] = fmaf(m0.w, w, acc[3]);
        acc[4] = fmaf(m1.x, w, acc[4]); acc[5] = fmaf(m1.y, w, acc[5]);
        acc[6] = fmaf(m1.z, w, acc[6]); acc[7] = fmaf(m1.w, w, acc[7]);
    }
    #pragma unroll 4
    for (int d = 0; d < 32; d++) {
        float w = LD<B>(lora_up, d * 256 + j);
        const float4 u0 = *reinterpret_cast<const float4*>(&sm.uT[d][0]);
        const float4 u1 = *reinterpret_cast<const float4*>(&sm.uT[d][4]);
        acc[0] = fmaf(u0.x, w, acc[0]); acc[1] = fmaf(u0.y, w, acc[1]);
        acc[2] = fmaf(u0.z, w, acc[2]); acc[3] = fmaf(u0.w, w, acc[3]);
        acc[4] = fmaf(u1.x, w, acc[4]); acc[5] = fmaf(u1.y, w, acc[5]);
        acc[6] = fmaf(u1.z, w, acc[6]); acc[7] = fmaf(u1.w, w, acc[7]);
    }
    #pragma unroll
    for (int s = 0; s < 8; s++)
        unsafeAtomicAdd(&agg[(size_t)sm.ei1s[s] * 256 + j], acc[s]);
}

__global__ __launch_bounds__(256) void edge_kernel_fb(
    const void* x, const int* edge_idx, const int* edge_attr,
    const void* node_elec, const void* lora_down, const void* lora_up,
    const void* emb_edge, const void* moa_w, const void* moa_s,
    const void* elec_lin, const void* lin_pre, float* agg, const int* flag)
{
    __shared__ EdgeSmemFB sm;
    const int j = threadIdx.x, g = blockIdx.x;
    if (*flag) edge_body_fb<true >(sm, x, edge_idx, edge_attr, node_elec, lora_down,
                                   lora_up, emb_edge, moa_w, moa_s, elec_lin, lin_pre, agg, g, j);
    else       edge_body_fb<false>(sm, x, edge_idx, edge_attr, node_elec, lora_down,
                                   lora_up, emb_edge, moa_w, moa_s, elec_lin, lin_pre, agg, g, j);
}

struct NodeSmemFB {
    __align__(16) float aggT[256][8];
    float gL[8][256];
    float vL[8][256];
    float ghat[256], vhat[256];
    float xxL[1024];
};

template<bool B>
__device__ void node_body_fb(NodeSmemFB& sm,
    const float* agg, const int* deg, const void* emb_deg,
    const void* gate_lin, const void* value_lin, const void* gate_kernel,
    const void* value_kernel, const void* act_bias, const void* post_kernel,
    void* out, int n0, int j)
{
    #pragma unroll
    for (int s = 0; s < 8; s++) sm.aggT[j][s] = agg[(size_t)(n0 + s) * 256 + j];
    __syncthreads();

    float ga[8], va[8];
    #pragma unroll
    for (int s = 0; s < 8; s++) { ga[s] = 0.f; va[s] = 0.f; }
    #pragma unroll 4
    for (int k = 0; k < 256; k++) {
        float wg = LD<B>(gate_lin,  k * 256 + j);
        float wv = LD<B>(value_lin, k * 256 + j);
        const float4 a0 = *reinterpret_cast<const float4*>(&sm.aggT[k][0]);
        const float4 a1 = *reinterpret_cast<const float4*>(&sm.aggT[k][4]);
        ga[0] = fmaf(a0.x, wg, ga[0]); va[0] = fmaf(a0.x, wv, va[0]);
        ga[1] = fmaf(a0.y, wg, ga[1]); va[1] = fmaf(a0.y, wv, va[1]);
        ga[2] = fmaf(a0.z, wg, ga[2]); va[2] = fmaf(a0.z, wv, va[2]);
        ga[3] = fmaf(a0.w, wg, ga[3]); va[3] = fmaf(a0.w, wv, va[3]);
        ga[4] = fmaf(a1.x, wg, ga[4]); va[4] = fmaf(a1.x, wv, va[4]);
        ga[5] = fmaf(a1.y, wg, ga[5]); va[5] = fmaf(a1.y, wv, va[5]);
        ga[6] = fmaf(a1.z, wg, ga[6]); va[6] = fmaf(a1.z, wv, va[6]);
        ga[7] = fmaf(a1.w, wg, ga[7]); va[7] = fmaf(a1.w, wv, va[7]);
    }
    __syncthreads();
    #pragma unroll
    for (int s = 0; s < 8; s++) { sm.gL[s][j] = ga[s]; sm.vL[s][j] = va[s]; }

    const int h = j >> 5, dd = j & 31, f0 = dd << 2;
    const float lo = 0.22360679774997896f, hi = 4.47213595499957939f;

    for (int s = 0; s < 8; s++) {
        __syncthreads();
        float gs = 0.f, vs = 0.f;
        #pragma unroll
        for (int d = 0; d < 32; d++) {
            float g = sm.gL[s][h * 32 + d];
            float v = sm.vL[s][h * 32 + d];
            gs = fmaf(g, g, gs); vs = fmaf(v, v, vs);
        }
        float grms = sqrtf(gs * (1.f / 32.f) + 1e-6f);
        float vrms = sqrtf(vs * (1.f / 32.f) + 1e-6f);
        float gv = sm.gL[s][j], vv = sm.vL[s][j];
        float bias = LD<B>(emb_deg, deg[n0 + s] * 256 + j);
        sm.ghat[j] = (gv / grms + bias) * 0.70710678118654752f;
        sm.vhat[j] = vv / vrms;
        __syncthreads();

        float a0 = 0.f, a1 = 0.f, a2 = 0.f, a3 = 0.f;
        float b0 = 0.f, b1 = 0.f, b2 = 0.f, b3 = 0.f;
        #pragma unroll 4
        for (int d = 0; d < 32; d++) {
            float gh = sm.ghat[h * 32 + d];
            float vh = sm.vhat[h * 32 + d];
            int base = h * 4096 + d * 128 + f0;
            a0 = fmaf(gh, LD<B>(gate_kernel,  base + 0), a0);
            a1 = fmaf(gh, LD<B>(gate_kernel,  base + 1), a1);
            a2 = fmaf(gh, LD<B>(gate_kernel,  base + 2), a2);
            a3 = fmaf(gh, LD<B>(gate_kernel,  base + 3), a3);
            b0 = fmaf(vh, LD<B>(value_kernel, base + 0), b0);
            b1 = fmaf(vh, LD<B>(value_kernel, base + 1), b1);
            b2 = fmaf(vh, LD<B>(value_kernel, base + 2), b2);
            b3 = fmaf(vh, LD<B>(value_kernel, base + 3), b3);
        }
        int fb = h * 128 + f0;
        a0 = fminf(fmaxf(softplusf(a0 + LD<B>(act_bias, fb + 0)), lo), hi);
        a1 = fminf(fmaxf(softplusf(a1 + LD<B>(act_bias, fb + 1)), lo), hi);
        a2 = fminf(fmaxf(softplusf(a2 + LD<B>(act_bias, fb + 2)), lo), hi);
        a3 = fminf(fmaxf(softplusf(a3 + LD<B>(act_bias, fb + 3)), lo), hi);
        sm.xxL[fb + 0] = a0 * b0; sm.xxL[fb + 1] = a1 * b1;
        sm.xxL[fb + 2] = a2 * b2; sm.xxL[fb + 3] = a3 * b3;
        __syncthreads();

        float o = 0.f;
        #pragma unroll 4
        for (int f = 0; f < 128; f++)
            o = fmaf(sm.xxL[h * 128 + f], LD<B>(post_kernel, h * 4096 + f * 32 + dd), o);
        if constexpr (B) ((u16*)out)[(size_t)(n0 + s) * 256 + j] = f2bf(o);
        else             ((float*)out)[(size_t)(n0 + s) * 256 + j] = o;
    }
}

__global__ __launch_bounds__(256) void node_kernel_fb(
    const float* agg, const int* deg, const void* emb_deg,
    const void* gate_lin, const void* value_lin, const void* gate_kernel,
    const void* value_kernel, const void* act_bias, const void* post_kernel,
    void* out, const int* flag)
{
    __shared__ NodeSmemFB sm;
    const int j = threadIdx.x, n0 = blockIdx.x * 8;
    if (*flag) node_body_fb<true >(sm, agg, deg, emb_deg, gate_lin, value_lin,
                                   gate_kernel, value_kernel, act_bias, post_kernel, out, n0, j);
    else       node_body_fb<false>(sm, agg, deg, emb_deg, gate_lin, value_lin,
                                   gate_kernel, value_kernel, act_bias, post_kernel, out, n0, j);
}

// ===========================================================================
extern "C" void kernel_launch(void* const* d_in, const int* in_sizes, int n_in,
                              void* d_out, int out_size, void* d_ws, size_t ws_size,
                              hipStream_t stream) {
    const void* x           = d_in[0];
    const int*  deg         = (const int*)d_in[1];
    const int*  edge_idx    = (const int*)d_in[2];
    const int*  edge_attr   = (const int*)d_in[3];
    const void* node_elec   = d_in[4];
    const void* lora_down   = d_in[5];
    const void* lora_up     = d_in[6];
    const void* emb_edge    = d_in[7];
    const void* moa_w       = d_in[8];
    const void* moa_s       = d_in[9];
    const void* elec_lin    = d_in[10];
    const void* emb_deg     = d_in[11];
    const void* lin_pre     = d_in[12];
    const void* gate_lin    = d_in[13];
    const void* gate_kernel = d_in[14];
    const void* value_lin   = d_in[15];
    const void* value_kernel= d_in[16];
    const void* act_bias    = d_in[17];
    const void* post_kernel = d_in[18];

    const size_t AGG_BYTES = (size_t)NN * 256 * 4;     // 61,440,000
    float* agg = (float*)d_ws;
    int* flag  = (int*)((char*)d_ws + AGG_BYTES);
    const size_t T_OFF = AGG_BYTES + 16;
    const size_t T_BYTES = (size_t)(3 * 65536 + 2 * 8192 + 3 * 32768) * 2; // 622,592
    const size_t NEEDED = T_OFF + T_BYTES;

    hipMemsetAsync(agg, 0, AGG_BYTES, stream);
    detect_kernel<<<1, 256, 0, stream>>>((const u16*)x, flag);

    if (ws_size >= NEEDED) {
        u16* gT  = (u16*)((char*)d_ws + T_OFF);
        u16* vT  = gT  + 65536;
        u16* lpT = vT  + 65536;
        u16* ldT = lpT + 65536;
        u16* luT = ldT + 8192;
        u16* gkT = luT + 8192;
        u16* vkT = gkT + 32768;
        u16* pkT = vkT + 32768;

        prep_kernel<<<128, 256, 0, stream>>>(
            gate_lin, value_lin, lin_pre, lora_down, lora_up,
            gate_kernel, value_kernel, post_kernel,
            gT, vT, lpT, ldT, luT, gkT, vkT, pkT, flag);

        edge_kernel_m<<<NE / 64, 256, 0, stream>>>(
            x, edge_idx, edge_attr, node_elec, emb_edge, moa_w, moa_s, elec_lin,
            ldT, luT, lpT, agg, flag);

        node_kernel_m<<<NN / 16, 256, 0, stream>>>(
            agg, deg, emb_deg, act_bias, gT, vT, gkT, vkT, pkT, d_out, flag);
    } else {
        edge_kernel_fb<<<NE / 8, 256, 0, stream>>>(
            x, edge_idx, edge_attr, node_elec, lora_down, lora_up, emb_edge,
            moa_w, moa_s, elec_lin, lin_pre, agg, flag);

        node_kernel_fb<<<NN / 8, 256, 0, stream>>>(
            agg, deg, emb_deg, gate_lin, value_lin, gate_kernel, value_kernel,
            act_bias, post_kernel, d_out, flag);
    }
}